// Round 8
// baseline (1413.861 us; speedup 1.0000x reference)
//
#include <hip/hip_runtime.h>

#define N_NODES 100000
#define N_EDGES 1600000
#define F_EDGE 48
#define F_GLOB 64
#define F_OUT 128
#define K_NA 176   // F_NODE + F_EDGE

// Native clang vector for nontemporal builtins (HIP float4 is a class type,
// which __builtin_nontemporal_* rejects). Same 16B layout/alignment.
typedef float f32x4 __attribute__((ext_vector_type(4)));

// ---- scatter: agg[recv[e]][f] += edges[e][f], float4 per thread ----
// unsafeAtomicAdd -> hardware global_atomic_add_f32 (device-scope past per-XCD
// L2, so cross-XCD correct). Plain atomicAdd may lower to a CAS loop under
// default flags -- catastrophic at 76.8M contended atomics.
// Edges are streamed once (307 MB > 256 MB L3) -> nontemporal loads.
__global__ __launch_bounds__(256) void scatter_kernel(
    const float* __restrict__ edges, const int* __restrict__ recv,
    float* __restrict__ agg) {
  unsigned idx4 = blockIdx.x * 256u + threadIdx.x;
  const unsigned total4 = (unsigned)N_EDGES * F_EDGE / 4u;  // 19.2M
  if (idx4 >= total4) return;
  unsigned base = idx4 * 4u;           // element index; 48%4==0 -> stays in one edge
  unsigned e = base / 48u;
  unsigned f = base - e * 48u;
  const f32x4 v = __builtin_nontemporal_load(
      reinterpret_cast<const f32x4*>(edges + base));
  float* dst = agg + (unsigned)recv[e] * 48u + f;
  unsafeAtomicAdd(dst + 0, v.x);
  unsafeAtomicAdd(dst + 1, v.y);
  unsafeAtomicAdd(dst + 2, v.z);
  unsafeAtomicAdd(dst + 3, v.w);
}

// ---- G[g][f] = sum_k globals_[g][k] * W[176+k][f] + b[f]  (8x128) ----
__global__ __launch_bounds__(256) void glob_kernel(
    const float* __restrict__ globals_, const float* __restrict__ W,
    const float* __restrict__ b, float* __restrict__ G) {
  int t = blockIdx.x * 256 + threadIdx.x;   // 0..1023
  int g = t >> 7, f = t & 127;
  float acc = b[f];
  const float* gv = globals_ + g * F_GLOB;
  const float* w  = W + K_NA * F_OUT + f;
  #pragma unroll 8
  for (int k = 0; k < F_GLOB; ++k) acc = fmaf(gv[k], w[k * F_OUT], acc);
  G[t] = acc;
}

// ---- out[n][f] = relu( [nodes|agg][n][:176] @ W[:176][f] + G[gid[n]][f] ) ----
// 64x128 tile, BK=16, 256 threads, 8x4 microtile. fp32 -> vector ALU (no fp32 MFMA).
__global__ __launch_bounds__(256) void node_gemm_kernel(
    const float* __restrict__ nodes, const float* __restrict__ agg,
    const float* __restrict__ W, const float* __restrict__ G,
    const int* __restrict__ gids, float* __restrict__ out) {
  __shared__ float As[16][68];    // [k][m], padded
  __shared__ float Bs[16][128];   // [k][n]
  const int tid = threadIdx.x;
  const int brow = blockIdx.x * 64;
  const int rows_left = N_NODES - brow;

  const int tn = tid & 31;        // cols 4*tn .. 4*tn+3
  const int tm = tid >> 5;        // rows 8*tm .. 8*tm+7
  const int arow = tid >> 2;      // A-load row 0..63
  const int aq = (tid & 3) * 4;   // A-load k-quad

  float acc[8][4];
  #pragma unroll
  for (int i = 0; i < 8; ++i)
    #pragma unroll
    for (int j = 0; j < 4; ++j) acc[i][j] = 0.f;

  for (int kt = 0; kt < 11; ++kt) {
    const int k0 = kt * 16;
    float4 av = make_float4(0.f, 0.f, 0.f, 0.f);
    if (arow < rows_left) {
      if (k0 < 128)
        av = *reinterpret_cast<const float4*>(nodes + (size_t)(brow + arow) * 128 + (k0 + aq));
      else
        av = *reinterpret_cast<const float4*>(agg + (size_t)(brow + arow) * 48 + (k0 - 128 + aq));
    }
    const float4 bv0 = *reinterpret_cast<const float4*>(W + (k0 + (tid >> 5)) * 128 + (tid & 31) * 4);
    const float4 bv1 = *reinterpret_cast<const float4*>(W + (k0 + 8 + (tid >> 5)) * 128 + (tid & 31) * 4);
    __syncthreads();
    As[aq + 0][arow] = av.x;
    As[aq + 1][arow] = av.y;
    As[aq + 2][arow] = av.z;
    As[aq + 3][arow] = av.w;
    *reinterpret_cast<float4*>(&Bs[tid >> 5][(tid & 31) * 4]) = bv0;
    *reinterpret_cast<float4*>(&Bs[(tid >> 5) + 8][(tid & 31) * 4]) = bv1;
    __syncthreads();
    #pragma unroll
    for (int k = 0; k < 16; ++k) {
      const float4 a01 = *reinterpret_cast<const float4*>(&As[k][tm * 8]);
      const float4 a23 = *reinterpret_cast<const float4*>(&As[k][tm * 8 + 4]);
      const float4 bq  = *reinterpret_cast<const float4*>(&Bs[k][tn * 4]);
      const float am[8] = {a01.x, a01.y, a01.z, a01.w, a23.x, a23.y, a23.z, a23.w};
      #pragma unroll
      for (int i = 0; i < 8; ++i) {
        acc[i][0] = fmaf(am[i], bq.x, acc[i][0]);
        acc[i][1] = fmaf(am[i], bq.y, acc[i][1]);
        acc[i][2] = fmaf(am[i], bq.z, acc[i][2]);
        acc[i][3] = fmaf(am[i], bq.w, acc[i][3]);
      }
    }
  }

  #pragma unroll
  for (int i = 0; i < 8; ++i) {
    const int row = brow + tm * 8 + i;
    if (row < N_NODES) {
      const float4 g4 = *reinterpret_cast<const float4*>(G + (size_t)gids[row] * F_OUT + tn * 4);
      f32x4 o;
      o.x = fmaxf(acc[i][0] + g4.x, 0.f);
      o.y = fmaxf(acc[i][1] + g4.y, 0.f);
      o.z = fmaxf(acc[i][2] + g4.z, 0.f);
      o.w = fmaxf(acc[i][3] + g4.w, 0.f);
      __builtin_nontemporal_store(o, reinterpret_cast<f32x4*>(out + (size_t)row * F_OUT + tn * 4));
    }
  }
}

extern "C" void kernel_launch(void* const* d_in, const int* in_sizes, int n_in,
                              void* d_out, int out_size, void* d_ws, size_t ws_size,
                              hipStream_t stream) {
  const float* nodes    = (const float*)d_in[0];
  const float* edges    = (const float*)d_in[1];
  const float* globals_ = (const float*)d_in[2];
  const float* W        = (const float*)d_in[3];
  const float* b        = (const float*)d_in[4];
  const int*   recv     = (const int*)d_in[5];
  const int*   gids     = (const int*)d_in[6];
  float* out = (float*)d_out;

  float* agg = (float*)d_ws;                                         // 100000*48 f32 = 19.2 MB
  float* G   = (float*)((char*)d_ws + (size_t)N_NODES * F_EDGE * 4); // 8*128 f32

  // ws is poisoned 0xAA before every launch -> zero the accumulator each call.
  (void)hipMemsetAsync(agg, 0, (size_t)N_NODES * F_EDGE * sizeof(float), stream);

  const unsigned total4 = (unsigned)N_EDGES * F_EDGE / 4u;
  scatter_kernel<<<(total4 + 255) / 256, 256, 0, stream>>>(edges, recv, agg);
  glob_kernel<<<4, 256, 0, stream>>>(globals_, W, b, G);
  node_gemm_kernel<<<(N_NODES + 63) / 64, 256, 0, stream>>>(nodes, agg, W, G, gids, out);
}